// Round 1
// 2193.630 us; speedup vs baseline: 1.2498x; 1.2498x over previous
//
#include <hip/hip_runtime.h>
#include <hip/hip_bf16.h>
#include <stdint.h>

typedef unsigned short ushort_t;

#define HID 512
#define FOURH 2048
#define BSZ 32
#define SLEN 50
#define TDEC 39
#define EMB 256
#define VOC 32000

using short8  = __attribute__((ext_vector_type(8))) short;
using float4v = __attribute__((ext_vector_type(4))) float;

__device__ inline float bf16lo(uint32_t u) { return __uint_as_float(u << 16); }
__device__ inline float bf16hi(uint32_t u) { return __uint_as_float(u & 0xffff0000u); }

__device__ inline ushort_t f32_to_bf16(float f) {
    uint32_t u = __float_as_uint(f);
    uint32_t r = (u + 0x7fffu + ((u >> 16) & 1u)) >> 16;
    return (ushort_t)r;
}

__device__ inline float sigmoid_f(float x) { return 1.0f / (1.0f + expf(-x)); }

// ---------------------------------------------------------------------------
// Runtime dtype detection. Probe = enc_b0 (values ~N(0,1)*0.05).
// Returns 1 if inputs are fp32 (wave-uniform).
// ---------------------------------------------------------------------------
__device__ inline int detect_f32(const ushort_t* __restrict__ probe) {
    int cnt = 0;
#pragma unroll
    for (int i = 0; i < 64; ++i) {
        int e = (probe[i] >> 7) & 0xFF;
        cnt += (e >= 0x8A);
    }
    return cnt > 0;
}

// ---------------------------------------------------------------------------
// Embedding gather -> bf16 pairs. Handles bf16 or fp32 source table.
// ---------------------------------------------------------------------------
__global__ void embed_kernel(const int* __restrict__ idx,
                             const void* __restrict__ emb,
                             uint32_t* __restrict__ out,
                             int total_u,
                             const ushort_t* __restrict__ probe)
{
    const int F32 = detect_f32(probe);
    int i = blockIdx.x * 256 + threadIdx.x;
    if (i >= total_u) return;
    int tok = i >> 7;          // EMB/2 = 128 uints per row
    int col = i & 127;
    int row = idx[tok];
    if (F32) {
        const float* ef = (const float*)emb + (size_t)row * EMB + col * 2;
        uint32_t lo = f32_to_bf16(ef[0]);
        uint32_t hi = f32_to_bf16(ef[1]);
        out[i] = lo | (hi << 16);
    } else {
        out[i] = ((const uint32_t*)emb)[(size_t)row * 128 + col];
    }
}

__device__ inline float load_bias(const void* __restrict__ bias, int n, int F32) {
    if (F32) return ((const float*)bias)[n];
    return __uint_as_float(((uint32_t)((const ushort_t*)bias)[n]) << 16);
}

__device__ inline void gload_lds16(const ushort_t* __restrict__ g, ushort_t* l) {
    __builtin_amdgcn_global_load_lds(
        (const __attribute__((address_space(1))) uint32_t*)g,
        (__attribute__((address_space(3))) uint32_t*)l,
        16, 0, 0);
}

// ---------------------------------------------------------------------------
// Tiled GEMM: C[M,N] = A[M,K](bf16 internal) @ W[N,K](bf16|fp32)^T + bias
// 128x128 tile, BK=64, 4 waves (2x2), single-buffered LDS (32 KB),
// global_load_lds for A (and W when bf16), reg-staged fp32->bf16 for W(fp32),
// XOR-swizzled LDS layout: logical (row, colbyte cb) stored at
//   row*128 + (cb ^ ((row&7)<<4))   -- conflict-free ds_read_b128.
// Staging writes LINEAR LDS dests (gl_lds requirement); the swizzle is
// applied by permuting the per-lane GLOBAL source column (involution).
// Grid: x = ceil(M/128) (fastest -> W-tile L2 reuse), y = N/128.
// M-tail: A-tile reads past M are memory-safe (inside d_out); stores guarded.
// SMODE 0: C = float* scratch (gate pre-activations)
// SMODE 1: C = d_out base; element idx = (32+m)*N+n; fp32 or bf16 per mode
// ---------------------------------------------------------------------------
template <int SMODE>
__global__ __launch_bounds__(256, 2)
void gemm_tile_kernel(const ushort_t* __restrict__ A,
                      const void* __restrict__ W,
                      const void* __restrict__ bias,
                      void* __restrict__ C,
                      int M, int N, int K,
                      const ushort_t* __restrict__ probe)
{
    const int F32 = detect_f32(probe);
    __shared__ ushort_t Alds[128 * 64];   // 16 KB
    __shared__ ushort_t Blds[128 * 64];   // 16 KB

    const int tid  = threadIdx.x;
    const int lane = tid & 63;
    const int wave = tid >> 6;
    const int l16  = lane & 15;
    const int l4   = lane >> 4;

    const int wm = (wave >> 1) * 64;      // wave's m-quadrant
    const int wn = (wave & 1) * 64;       // wave's n-quadrant

    const int mbase = blockIdx.x * 128;
    const int nbase = blockIdx.y * 128;

    // staging lane geometry (per 1 KB chunk): 8 rows x 64 cols bf16
    const int sr   = lane >> 3;                   // sub-row 0..7 (== row&7)
    const int scol = ((lane & 7) ^ sr) * 8;       // swizzled source col (elems)

    float4v acc[4][4];
#pragma unroll
    for (int i = 0; i < 4; ++i)
#pragma unroll
        for (int j = 0; j < 4; ++j) acc[i][j] = (float4v){0.f, 0.f, 0.f, 0.f};

    for (int k0 = 0; k0 < K; k0 += 64) {
        __syncthreads();   // all waves done reading previous tile

        // ---- stage A (always bf16): 4 x 1KB chunks per wave
#pragma unroll
        for (int c = 0; c < 4; ++c) {
            int chunk = wave * 4 + c;             // 0..15
            int row   = chunk * 8 + sr;           // tile row 0..127
            gload_lds16(A + (size_t)(mbase + row) * K + k0 + scol,
                        Alds + chunk * 512);
        }
        // ---- stage W
        if (F32) {
#pragma unroll
            for (int c = 0; c < 4; ++c) {
                int chunk = wave * 4 + c;
                int row   = chunk * 8 + sr;
                const float* gp = (const float*)W + (size_t)(nbase + row) * K + k0 + scol;
                float4v f0 = *(const float4v*)gp;
                float4v f1 = *(const float4v*)(gp + 4);
                short8 v;
#pragma unroll
                for (int j = 0; j < 4; ++j) v[j]     = (short)f32_to_bf16(f0[j]);
#pragma unroll
                for (int j = 0; j < 4; ++j) v[4 + j] = (short)f32_to_bf16(f1[j]);
                *(short8*)(Blds + chunk * 512 + lane * 8) = v;   // linear dest
            }
        } else {
#pragma unroll
            for (int c = 0; c < 4; ++c) {
                int chunk = wave * 4 + c;
                int row   = chunk * 8 + sr;
                gload_lds16((const ushort_t*)W + (size_t)(nbase + row) * K + k0 + scol,
                            Blds + chunk * 512);
            }
        }
        __syncthreads();   // compiler drains vmcnt/lgkmcnt before barrier

        // ---- fragments (swizzled read) + MFMA
        short8 af[4][2], bf[4][2];
#pragma unroll
        for (int mi = 0; mi < 4; ++mi) {
            int row = wm + mi * 16 + l16;
#pragma unroll
            for (int kk = 0; kk < 2; ++kk) {
                int cb = (kk * 64 + l4 * 16) ^ ((l16 & 7) << 4);
                af[mi][kk] = *(const short8*)((const char*)Alds + row * 128 + cb);
            }
        }
#pragma unroll
        for (int ni = 0; ni < 4; ++ni) {
            int row = wn + ni * 16 + l16;
#pragma unroll
            for (int kk = 0; kk < 2; ++kk) {
                int cb = (kk * 64 + l4 * 16) ^ ((l16 & 7) << 4);
                bf[ni][kk] = *(const short8*)((const char*)Blds + row * 128 + cb);
            }
        }
#pragma unroll
        for (int mi = 0; mi < 4; ++mi)
#pragma unroll
            for (int ni = 0; ni < 4; ++ni) {
                acc[mi][ni] = __builtin_amdgcn_mfma_f32_16x16x32_bf16(
                    af[mi][0], bf[ni][0], acc[mi][ni], 0, 0, 0);
                acc[mi][ni] = __builtin_amdgcn_mfma_f32_16x16x32_bf16(
                    af[mi][1], bf[ni][1], acc[mi][ni], 0, 0, 0);
            }
    }

    // ---- epilogue: C/D mapping col=l16, row=l4*4+r (verified convention)
#pragma unroll
    for (int mi = 0; mi < 4; ++mi) {
#pragma unroll
        for (int ni = 0; ni < 4; ++ni) {
            int n = nbase + wn + ni * 16 + l16;
            float bv = load_bias(bias, n, F32);
#pragma unroll
            for (int r = 0; r < 4; ++r) {
                int m = mbase + wm + mi * 16 + l4 * 4 + r;
                if (m < M) {
                    float v = acc[mi][ni][r] + bv;
                    if (SMODE == 0) {
                        ((float*)C)[(size_t)m * N + n] = v;
                    } else {
                        size_t idx = (size_t)(BSZ + m) * N + n;  // skip zero timestep
                        if (F32) ((float*)C)[idx] = v;
                        else     ((ushort_t*)C)[idx] = f32_to_bf16(v);
                    }
                }
            }
        }
    }
}

// ---------------------------------------------------------------------------
// One LSTM timestep: g = xih(fp32, precomputed) + h_in @ Whh^T ; cell update.
// ---------------------------------------------------------------------------
__global__ void lstm_step_kernel(const float* __restrict__ xih,     // (32,2048) this t
                                 const ushort_t* __restrict__ h_in, // (32,512) bf16
                                 ushort_t* __restrict__ h_out,      // (32,512) bf16
                                 float* __restrict__ c,             // (32,512) fp32
                                 const void* __restrict__ Whh,      // (2048,512)
                                 ushort_t* __restrict__ ys,         // (32,512) or null
                                 const ushort_t* __restrict__ probe)
{
    const int F32 = detect_f32(probe);
    __shared__ uint32_t h_lds[BSZ * 257];   // padded rows
    __shared__ uint32_t w_lds[8 * 256];
    __shared__ float    g_lds[8][BSZ];

    const int tid = threadIdx.x;
    const int j0  = blockIdx.x * 2;

    const uint32_t* h32 = (const uint32_t*)h_in;
#pragma unroll
    for (int i = 0; i < 32; ++i) {                 // 8192 uints
        int idx = tid + i * 256;
        int row = idx >> 8, col = idx & 255;
        h_lds[row * 257 + col] = h32[idx];
    }

#pragma unroll
    for (int i = 0; i < 8; ++i) {                  // 2048 uints (8 Whh rows)
        int idx  = tid + i * 256;
        int lrr  = idx >> 8, col = idx & 255;
        int gate = lrr >> 1, jl = lrr & 1;
        size_t wrow = (size_t)(gate * HID + j0 + jl);
        if (F32) {
            const float* wf = (const float*)Whh + wrow * HID + col * 2;
            uint32_t lo = f32_to_bf16(wf[0]);
            uint32_t hi = f32_to_bf16(wf[1]);
            w_lds[lrr * 256 + col] = lo | (hi << 16);
        } else {
            w_lds[lrr * 256 + col] = ((const uint32_t*)Whh)[wrow * 256 + col];
        }
    }
    __syncthreads();

    const int b    = tid & 31;
    const int lr   = tid >> 5;          // (gate<<1)|jl
    const int gate = lr >> 1;
    const int jl   = lr & 1;

    float dot = xih[b * FOURH + gate * HID + j0 + jl];
    const uint32_t* hr = &h_lds[b * 257];
    const uint32_t* wr = &w_lds[lr * 256];
    float s0 = 0.f, s1 = 0.f;
#pragma unroll 8
    for (int k = 0; k < 256; ++k) {
        uint32_t hu = hr[k], wu = wr[k];
        s0 += bf16lo(hu) * bf16lo(wu);
        s1 += bf16hi(hu) * bf16hi(wu);
    }
    g_lds[lr][b] = dot + s0 + s1;
    __syncthreads();

    if (tid < 64) {
        int b2 = tid & 31, jl2 = tid >> 5;
        int j  = j0 + jl2;
        float gi = g_lds[(0 << 1) | jl2][b2];
        float gf = g_lds[(1 << 1) | jl2][b2];
        float gg = g_lds[(2 << 1) | jl2][b2];
        float go = g_lds[(3 << 1) | jl2][b2];
        float cold = c[b2 * HID + j];
        float cn = sigmoid_f(gf) * cold + sigmoid_f(gi) * tanhf(gg);
        float hn = sigmoid_f(go) * tanhf(cn);
        c[b2 * HID + j] = cn;
        ushort_t hb = f32_to_bf16(hn);
        h_out[b2 * HID + j] = hb;
        if (ys) ys[b2 * HID + j] = hb;
    }
}

// ---------------------------------------------------------------------------
// Zero the first output timestep (elements [0, 32*VOC)), dtype per mode.
// ---------------------------------------------------------------------------
__global__ void zero_row_kernel(void* __restrict__ outv,
                                const ushort_t* __restrict__ probe)
{
    const int F32 = detect_f32(probe);
    int i = blockIdx.x * 256 + threadIdx.x;
    if (i >= BSZ * VOC) return;
    if (F32) ((uint32_t*)outv)[i] = 0u;
    else     ((ushort_t*)outv)[i] = 0;
}

// ---------------------------------------------------------------------------
// Scratch layout inside d_out:
//   dy1 (bf16, <=1.31 MB incl. tail rows) at byte 0 — projection writes start
//     at byte 32*VOC*esize >= 2.048 MB, so dy1 survives until projection reads;
//   arena at byte 4 MiB for all other intermediates — dead before projection.
// GEMM M-tail reads (up to 128-row round-up) stay inside d_out — safe.
// ---------------------------------------------------------------------------
extern "C" void kernel_launch(void* const* d_in, const int* in_sizes, int n_in,
                              void* d_out, int out_size, void* d_ws, size_t ws_size,
                              hipStream_t stream)
{
    const int*      src      = (const int*)d_in[0];
    const int*      trg      = (const int*)d_in[1];
    const void*     enc_emb  = d_in[2];
    const void*     enc_Wih0 = d_in[3];
    const void*     enc_Whh0 = d_in[4];
    const void*     enc_b0   = d_in[5];
    const void*     enc_Wih1 = d_in[6];
    const void*     enc_Whh1 = d_in[7];
    const void*     enc_b1   = d_in[8];
    const void*     dec_emb  = d_in[9];
    const void*     dec_Wih0 = d_in[10];
    const void*     dec_Whh0 = d_in[11];
    const void*     dec_b0   = d_in[12];
    const void*     dec_Wih1 = d_in[13];
    const void*     dec_Whh1 = d_in[14];
    const void*     dec_b1   = d_in[15];
    const void*     out_W    = d_in[16];
    const void*     out_b    = d_in[17];

    const ushort_t* probe = (const ushort_t*)enc_b0;   // dtype probe

    const int ME = SLEN * BSZ;   // 1600
    const int MD = TDEC * BSZ;   // 1248

    ushort_t* dy1 = (ushort_t*)d_out;

    char*  arena = (char*)d_out + (4u << 20);          // 4 MiB
    size_t aoff  = 0;
    auto acarve = [&](size_t bytes) -> void* {
        void* p = arena + aoff;
        aoff = (aoff + bytes + 255) & ~(size_t)255;
        return p;
    };
    const size_t HSTATE = (size_t)BSZ * HID;                       // 16384 elems
    float*    Xbig = (float*)acarve((size_t)ME * FOURH * 4);       // 13.1 MB fp32
    ushort_t* X0   = (ushort_t*)acarve((size_t)ME * EMB * 2);
    ushort_t* DX0  = (ushort_t*)acarve((size_t)MD * EMB * 2);
    ushort_t* ys0  = (ushort_t*)acarve((size_t)ME * HID * 2);
    ushort_t* dy0  = (ushort_t*)acarve((size_t)MD * HID * 2);
    ushort_t* h0b  = (ushort_t*)acarve(2 * HSTATE * 2);            // dbl-buffered h
    float*    c0b  = (float*)acarve(HSTATE * 4);
    ushort_t* h1b  = (ushort_t*)acarve(2 * HSTATE * 2);
    float*    c1b  = (float*)acarve(HSTATE * 4);

    // init recurrent states
    hipMemsetAsync(h0b, 0, HSTATE * 2, stream);
    hipMemsetAsync(c0b, 0, HSTATE * 4, stream);
    hipMemsetAsync(h1b, 0, HSTATE * 2, stream);
    hipMemsetAsync(c1b, 0, HSTATE * 4, stream);

    // embeddings
    {
        int tu = ME * (EMB / 2);
        embed_kernel<<<(tu + 255) / 256, 256, 0, stream>>>(
            src, enc_emb, (uint32_t*)X0, tu, probe);
        int td = MD * (EMB / 2);
        embed_kernel<<<(td + 255) / 256, 256, 0, stream>>>(
            trg, dec_emb, (uint32_t*)DX0, td, probe);
    }

    const size_t XIH_T = (size_t)BSZ * FOURH;
    const int MTE = (ME + 127) / 128;   // 13 m-tiles (encoder GEMMs)
    const int MTD = (MD + 127) / 128;   // 10 m-tiles (decoder GEMMs / proj)

    // encoder layer 0
    gemm_tile_kernel<0><<<dim3(MTE, FOURH / 128), 256, 0, stream>>>(
        X0, enc_Wih0, enc_b0, Xbig, ME, FOURH, EMB, probe);
    for (int t = 0; t < SLEN; ++t) {
        lstm_step_kernel<<<256, 256, 0, stream>>>(
            Xbig + (size_t)t * XIH_T,
            h0b + (t & 1) * HSTATE, h0b + ((t + 1) & 1) * HSTATE,
            c0b, enc_Whh0, ys0 + (size_t)t * HSTATE, probe);
    }
    // encoder layer 1 (only final state needed)
    gemm_tile_kernel<0><<<dim3(MTE, FOURH / 128), 256, 0, stream>>>(
        ys0, enc_Wih1, enc_b1, Xbig, ME, FOURH, HID, probe);
    for (int t = 0; t < SLEN; ++t) {
        lstm_step_kernel<<<256, 256, 0, stream>>>(
            Xbig + (size_t)t * XIH_T,
            h1b + (t & 1) * HSTATE, h1b + ((t + 1) & 1) * HSTATE,
            c1b, enc_Whh1, (ushort_t*)nullptr, probe);
    }
    // 50 steps (even): final h at parity 0 -> decoder t=0 reads parity 0.

    // decoder layer 0 (continues h0b/c0b)
    gemm_tile_kernel<0><<<dim3(MTD, FOURH / 128), 256, 0, stream>>>(
        DX0, dec_Wih0, dec_b0, Xbig, MD, FOURH, EMB, probe);
    for (int t = 0; t < TDEC; ++t) {
        lstm_step_kernel<<<256, 256, 0, stream>>>(
            Xbig + (size_t)t * XIH_T,
            h0b + (t & 1) * HSTATE, h0b + ((t + 1) & 1) * HSTATE,
            c0b, dec_Whh0, dy0 + (size_t)t * HSTATE, probe);
    }
    // decoder layer 1 (continues h1b/c1b)
    gemm_tile_kernel<0><<<dim3(MTD, FOURH / 128), 256, 0, stream>>>(
        dy0, dec_Wih1, dec_b1, Xbig, MD, FOURH, HID, probe);
    for (int t = 0; t < TDEC; ++t) {
        lstm_step_kernel<<<256, 256, 0, stream>>>(
            Xbig + (size_t)t * XIH_T,
            h1b + (t & 1) * HSTATE, h1b + ((t + 1) & 1) * HSTATE,
            c1b, dec_Whh1, dy1 + (size_t)t * HSTATE, probe);
    }

    // projection: reads dy1 (bytes [0,1.28MB)) + out_W/out_b; writes
    // elements [32*VOC, 1280*VOC) of d_out. Arena is dead. m-fastest grid.
    gemm_tile_kernel<1><<<dim3(MTD, VOC / 128), 256, 0, stream>>>(
        dy1, out_W, out_b, d_out, MD, VOC, HID, probe);

    // zero first output timestep (elements [0, 32*VOC)) — also wipes dy1.
    zero_row_kernel<<<(BSZ * VOC + 255) / 256, 256, 0, stream>>>(d_out, probe);
}